// Round 1
// baseline (341.785 us; speedup 1.0000x reference)
//
#include <hip/hip_runtime.h>
#include <hip/hip_bf16.h>

// Problem constants
constexpr int BB = 8192;   // batch rows
constexpr int CC = 2048;   // classes
constexpr int FF = 2048;   // features (K)

typedef __bf16 bf16x8 __attribute__((ext_vector_type(8)));
typedef float  f32x4  __attribute__((ext_vector_type(4)));

typedef __attribute__((address_space(1))) unsigned int gu32;
typedef __attribute__((address_space(3))) unsigned int lu32;

// async global->LDS, 16B per lane. LDS side is wave-uniform base + lane*16.
__device__ __forceinline__ void async_copy16(const void* g, void* l) {
    __builtin_amdgcn_global_load_lds(
        (gu32*)(unsigned long long)g,
        (lu32*)(unsigned int)(unsigned long long)l,
        16, 0, 0);
}

// ---------------------------------------------------------------------------
// prep (merged): rows [0,BB) = x scaled by 1/var; rows [BB,BB+CC) = means.
// emit bf16 row + fp32 sum of squares. 256 thr/row, 8 elems/thread.
// ---------------------------------------------------------------------------
__global__ void prep_rows(const float* __restrict__ x,
                          const float* __restrict__ means,
                          unsigned short* __restrict__ xb,
                          unsigned short* __restrict__ mb,
                          float* __restrict__ x2,
                          float* __restrict__ m2,
                          const float* __restrict__ varp) {
    const int blk = blockIdx.x;
    const bool isx = blk < BB;
    const int row = isx ? blk : blk - BB;
    const int t = threadIdx.x;
    const float scale = isx ? (1.0f / varp[0]) : 1.0f;
    const float* in = isx ? x : means;
    unsigned short* outb = isx ? xb : mb;
    const size_t base = (size_t)row * FF + (size_t)t * 8;
    const float4 a = *(const float4*)(in + base);
    const float4 b = *(const float4*)(in + base + 4);
    float v[8] = {a.x * scale, a.y * scale, a.z * scale, a.w * scale,
                  b.x * scale, b.y * scale, b.z * scale, b.w * scale};
    float s = 0.0f;
    bf16x8 h;
#pragma unroll
    for (int i = 0; i < 8; ++i) {
        s += v[i] * v[i];
        h[i] = (__bf16)v[i];
    }
    *(bf16x8*)(outb + base) = h;
#pragma unroll
    for (int off = 32; off > 0; off >>= 1) s += __shfl_down(s, off);
    __shared__ float red[4];
    if ((t & 63) == 0) red[t >> 6] = s;
    __syncthreads();
    if (t == 0) {
        float tot = (red[0] + red[1]) + (red[2] + red[3]);
        if (isx) x2[row] = tot; else m2[row] = tot;
    }
}

// ---------------------------------------------------------------------------
// GEMM cross[b][c] = sum_f xs[b][f]*means[c][f]  (row-major, K contig: NT)
//
// 256x256 tile, 512 thr = 8 waves (2M x 4N), per-wave output 128x64 via
// 8x4 of v_mfma_f32_16x16x32_bf16.  K is consumed in chunks of 32 through a
// RING of 4 LDS slots (slot = A 256x32 + B 256x32 bf16 = 32 KB; 128 KiB total
// -> 1 block/CU, grid = 256 = chip-exact).
//
// Pipeline (T3+T4): per chunk ONE raw s_barrier + ONE counted vmcnt — never a
// full drain in the main loop.  Steady state: entering chunk c, each wave has
// chunks {c,c+1,c+2} in flight (12 loads, 4/chunk); vmcnt(8) lands chunk c,
// the barrier makes it cross-wave, then chunk c+3 is issued into the slot
// whose readers this barrier just proved done.  Lead = 3 chunks (~930 cyc)
// ~ HBM latency.  Compiler lgkm waits (reads feed MFMAs before the next
// barrier) guarantee each slot is read-drained one barrier before its reuse.
//
// LDS rows are 64B (4 x 16B chunks); physical chunk c' = c ^ (row&3), applied
// by pre-swizzling the global source (linear DMA dest) and XORing on read.
// Epilogue: d = sqrt(max(x2+m2-2c,0)); expo=-d, cum=d.
// ---------------------------------------------------------------------------
__global__ __launch_bounds__(512, 2) void gemm_epi(
    const unsigned short* __restrict__ A,   // xs  bf16 [BB][FF]
    const unsigned short* __restrict__ Bm,  // means bf16 [CC][FF]
    const float* __restrict__ x2,           // [BB]
    const float* __restrict__ m2,           // [CC]
    float* __restrict__ expo,               // [BB][CC]
    float* __restrict__ cum) {              // [BB][CC]
    __shared__ __align__(16) unsigned short As[4][256 * 32];
    __shared__ __align__(16) unsigned short Bs[4][256 * 32];

    const int t = threadIdx.x;
    const int wave = t >> 6, lane = t & 63;
    // XCD-chunked swizzle: dispatcher round-robins bx%8 across XCDs, so give
    // XCD x the 32 blocks of bn == x  -> its 1MB B-panel stays in its L2.
    const int bx = blockIdx.x;
    const int lid = (bx & 7) * 32 + (bx >> 3);
    const int bm = lid & 31, bn = lid >> 5;            // 32 x 8 grid
    const int rowA0 = bm * 256, rowB0 = bn * 256;
    const int wm = wave >> 2, wn = wave & 3;

    // --- staging constants: wave-instruction writes 16 rows x 64B linear.
    // lane -> row-in-group lane>>2, slot-in-row lane&3; source 16B-chunk is
    // the inverse swizzle  c = slot ^ (row&3).
    const int sr = lane >> 2;                           // 0..15
    const int sc = ((lane & 3) ^ (sr & 3)) * 8;         // source col (shorts)
    const unsigned short* gA0 = A  + (size_t)(rowA0 +       wave * 16 + sr) * FF + sc;
    const unsigned short* gA1 = A  + (size_t)(rowA0 + 128 + wave * 16 + sr) * FF + sc;
    const unsigned short* gB0 = Bm + (size_t)(rowB0 +       wave * 16 + sr) * FF + sc;
    const unsigned short* gB1 = Bm + (size_t)(rowB0 + 128 + wave * 16 + sr) * FF + sc;
    const int ldsOff = wave * 16 * 32;                  // shorts

    // --- fragment read constants (mfma 16x16x32: row = lane&15, k-chunk = lane>>4)
    const int rl = lane & 15, kb = lane >> 4;
    const int pcol = (kb ^ (rl & 3)) * 8;               // phys col (shorts)
    const int arow = (wm * 128 + rl) * 32 + pcol;
    const int brow = (wn * 64  + rl) * 32 + pcol;

    f32x4 acc[8][4] = {};

    auto STAGE = [&](int slot, int kc) {
        const int ko = kc * 32;
        async_copy16(gA0 + ko, &As[slot][ldsOff]);
        async_copy16(gA1 + ko, &As[slot][128 * 32 + ldsOff]);
        async_copy16(gB0 + ko, &Bs[slot][ldsOff]);
        async_copy16(gB1 + ko, &Bs[slot][128 * 32 + ldsOff]);
    };
    auto COMPUTE = [&](int slot) {
        bf16x8 af[8], bfr[4];
#pragma unroll
        for (int i = 0; i < 8; ++i) af[i] = *(const bf16x8*)&As[slot][arow + i * 16 * 32];
#pragma unroll
        for (int j = 0; j < 4; ++j) bfr[j] = *(const bf16x8*)&Bs[slot][brow + j * 16 * 32];
        __builtin_amdgcn_s_setprio(1);
#pragma unroll
        for (int i = 0; i < 8; ++i)
#pragma unroll
            for (int j = 0; j < 4; ++j)
                acc[i][j] = __builtin_amdgcn_mfma_f32_16x16x32_bf16(af[i], bfr[j], acc[i][j], 0, 0, 0);
        __builtin_amdgcn_s_setprio(0);
        __builtin_amdgcn_sched_barrier(0);   // pin MFMAs (and their lgkm waits)
                                             // above the next barrier
    };

    // prologue: 3 chunks in flight
    STAGE(0, 0); STAGE(1, 1); STAGE(2, 2);

    // main loop: chunks 0..59, staging 3..62. vmcnt(8) = 12 outstanding - 4.
    for (int c = 0; c < 60; c += 4) {
#pragma unroll
        for (int u = 0; u < 4; ++u) {
            asm volatile("s_waitcnt vmcnt(8)" ::: "memory");
            __builtin_amdgcn_s_barrier();
            __builtin_amdgcn_sched_barrier(0);
            STAGE((u + 3) & 3, c + u + 3);
            COMPUTE(u);
        }
    }
    // tail: chunks 60..63 (stage only 63), draining vmcnt 8 -> 8 -> 4 -> 0
    asm volatile("s_waitcnt vmcnt(8)" ::: "memory");
    __builtin_amdgcn_s_barrier();
    __builtin_amdgcn_sched_barrier(0);
    STAGE(3, 63);
    COMPUTE(0);
    asm volatile("s_waitcnt vmcnt(8)" ::: "memory");
    __builtin_amdgcn_s_barrier();
    __builtin_amdgcn_sched_barrier(0);
    COMPUTE(1);
    asm volatile("s_waitcnt vmcnt(4)" ::: "memory");
    __builtin_amdgcn_s_barrier();
    __builtin_amdgcn_sched_barrier(0);
    COMPUTE(2);
    asm volatile("s_waitcnt vmcnt(0)" ::: "memory");
    __builtin_amdgcn_s_barrier();
    __builtin_amdgcn_sched_barrier(0);
    COMPUTE(3);

    // epilogue: C/D layout col = lane&15, row = (lane>>4)*4 + reg  [m89/m91]
    const int ln = lane & 15, lq = lane >> 4;
    const int grow0 = rowA0 + wm * 128 + lq * 4;
    const int gcol0 = rowB0 + wn * 64 + ln;
    float m2v[4];
#pragma unroll
    for (int j = 0; j < 4; ++j) m2v[j] = m2[gcol0 + j * 16];

#pragma unroll
    for (int i = 0; i < 8; ++i) {
        float x2r[4];
#pragma unroll
        for (int r = 0; r < 4; ++r) x2r[r] = x2[grow0 + i * 16 + r];
#pragma unroll
        for (int j = 0; j < 4; ++j)
#pragma unroll
            for (int r = 0; r < 4; ++r) {
                const float d2 = x2r[r] + m2v[j] - 2.0f * acc[i][j][r];
                const float d = sqrtf(fmaxf(d2, 0.0f));
                const size_t idx = (size_t)(grow0 + i * 16 + r) * CC + (gcol0 + j * 16);
                __builtin_nontemporal_store(d, &cum[idx]);  // never re-read
                expo[idx] = -d;                              // re-read by softmax
            }
    }
}

// ---------------------------------------------------------------------------
// softmax over each row of exponent -> probs. one block (256 thr) per row.
// No max-subtraction: d = sqrt(x2+m2-2c) <= sqrt(~4500) < 68, so
// exp(-d) >= 3e-30 >> FLT_MIN — unshifted exp is safe and exact enough.
// ---------------------------------------------------------------------------
__global__ void softmax_rows(const float* __restrict__ e, float* __restrict__ p) {
    const int row = blockIdx.x;
    const int t = threadIdx.x;
    const size_t base = (size_t)row * CC + (size_t)t * 8;
    const float4 a = *(const float4*)(e + base);
    const float4 b = *(const float4*)(e + base + 4);
    float ev[8] = {__expf(a.x), __expf(a.y), __expf(a.z), __expf(a.w),
                   __expf(b.x), __expf(b.y), __expf(b.z), __expf(b.w)};
    float s = 0.0f;
#pragma unroll
    for (int i = 0; i < 8; ++i) s += ev[i];
#pragma unroll
    for (int off = 32; off > 0; off >>= 1) s += __shfl_down(s, off);
    __shared__ float reds[4];
    if ((t & 63) == 0) reds[t >> 6] = s;
    __syncthreads();
    s = (reds[0] + reds[1]) + (reds[2] + reds[3]);
    const float inv = 1.0f / s;

    f32x4 o0 = {ev[0] * inv, ev[1] * inv, ev[2] * inv, ev[3] * inv};
    f32x4 o1 = {ev[4] * inv, ev[5] * inv, ev[6] * inv, ev[7] * inv};
    __builtin_nontemporal_store(o0, (f32x4*)(p + base));
    __builtin_nontemporal_store(o1, (f32x4*)(p + base + 4));
}

// ---------------------------------------------------------------------------
extern "C" void kernel_launch(void* const* d_in, const int* in_sizes, int n_in,
                              void* d_out, int out_size, void* d_ws, size_t ws_size,
                              hipStream_t stream) {
    const float* x     = (const float*)d_in[0];   // [BB][FF]
    const float* means = (const float*)d_in[1];   // [CC][FF]
    const float* var   = (const float*)d_in[2];   // [1]
    float* out = (float*)d_out;

    // workspace layout: xb bf16 [BB*FF] | mb bf16 [CC*FF] | x2 f32[BB] | m2 f32[CC]
    unsigned short* xb = (unsigned short*)d_ws;
    unsigned short* mb = xb + (size_t)BB * FF;
    float* x2 = (float*)(mb + (size_t)CC * FF);
    float* m2 = x2 + BB;

    float* probs = out;                          // output 0
    float* expo  = out + (size_t)BB * CC;        // output 1
    float* cum   = expo + (size_t)BB * CC;       // output 2

    prep_rows<<<BB + CC, 256, 0, stream>>>(x, means, xb, mb, x2, m2, var);
    gemm_epi<<<(BB / 256) * (CC / 256), 512, 0, stream>>>(xb, mb, x2, m2, expo, cum);
    softmax_rows<<<BB, 256, 0, stream>>>(expo, probs);
}

// Round 2
// 335.493 us; speedup vs baseline: 1.0188x; 1.0188x over previous
//
#include <hip/hip_runtime.h>
#include <hip/hip_bf16.h>

// Problem constants
constexpr int BB = 8192;   // batch rows
constexpr int CC = 2048;   // classes
constexpr int FF = 2048;   // features (K)

typedef __bf16 bf16x8 __attribute__((ext_vector_type(8)));
typedef float  f32x4  __attribute__((ext_vector_type(4)));

typedef __attribute__((address_space(1))) unsigned int gu32;
typedef __attribute__((address_space(3))) unsigned int lu32;

// async global->LDS, 16B per lane. LDS side is wave-uniform base + lane*16.
__device__ __forceinline__ void async_copy16(const void* g, void* l) {
    __builtin_amdgcn_global_load_lds(
        (gu32*)(unsigned long long)g,
        (lu32*)(unsigned int)(unsigned long long)l,
        16, 0, 0);
}

// ---------------------------------------------------------------------------
// prep (merged): rows [0,BB) = x scaled by 1/var; rows [BB,BB+CC) = means.
// emit bf16 row + fp32 sum of squares. 256 thr/row, 8 elems/thread.
// ---------------------------------------------------------------------------
__global__ void prep_rows(const float* __restrict__ x,
                          const float* __restrict__ means,
                          unsigned short* __restrict__ xb,
                          unsigned short* __restrict__ mb,
                          float* __restrict__ x2,
                          float* __restrict__ m2,
                          const float* __restrict__ varp) {
    const int blk = blockIdx.x;
    const bool isx = blk < BB;
    const int row = isx ? blk : blk - BB;
    const int t = threadIdx.x;
    const float scale = isx ? (1.0f / varp[0]) : 1.0f;
    const float* in = isx ? x : means;
    unsigned short* outb = isx ? xb : mb;
    const size_t base = (size_t)row * FF + (size_t)t * 8;
    const float4 a = *(const float4*)(in + base);
    const float4 b = *(const float4*)(in + base + 4);
    float v[8] = {a.x * scale, a.y * scale, a.z * scale, a.w * scale,
                  b.x * scale, b.y * scale, b.z * scale, b.w * scale};
    float s = 0.0f;
    bf16x8 h;
#pragma unroll
    for (int i = 0; i < 8; ++i) {
        s += v[i] * v[i];
        h[i] = (__bf16)v[i];
    }
    *(bf16x8*)(outb + base) = h;
#pragma unroll
    for (int off = 32; off > 0; off >>= 1) s += __shfl_down(s, off);
    __shared__ float red[4];
    if ((t & 63) == 0) red[t >> 6] = s;
    __syncthreads();
    if (t == 0) {
        float tot = (red[0] + red[1]) + (red[2] + red[3]);
        if (isx) x2[row] = tot; else m2[row] = tot;
    }
}

// ---------------------------------------------------------------------------
// GEMM cross[b][c] = sum_f xs[b][f]*means[c][f]  (row-major, K contig: NT)
//
// 256x256 tile, 512 thr = 8 waves (2M x 4N), per-wave output 128x64 via
// 8x4 of v_mfma_f32_16x16x32_bf16.  K consumed in chunks of 32 through a
// RING of 4 LDS slots (slot = A 256x32 + B 256x32 bf16 = 32 KB; 128 KiB
// total -> 1 block/CU, grid = 256 = chip-exact).
//
// Per phase u: [vmcnt(8) -> own chunk-u loads landed] [s_barrier -> all
// waves' loads landed] [sched_barrier: the ONLY pin — keeps reads below the
// cross-wave confirmation] [STAGE chunk u+3 into slot (u-1)&3: safe, its
// readers in phase u-1 completed their ds_reads before passing barrier_u]
// [12 ds_read_b128 (B first) + 32 MFMA].  No other scheduling pins (m141:
// over-pinning = 510 TF).  Waves overlap within a phase: one wave's MFMAs
// run while others issue reads/stages — counted vmcnt never drains in-loop.
//
// LDS rows 64 B (4 x 16B chunks); phys chunk c' = c ^ ((row>>1)&3):
// start banks 16*(row&1) + 4*(c') cover {0,4,..,28}, 2 lanes/bank within a
// 16-lane frag read = 2-way = free (m136).  Same XOR pre-applied to the
// global source (DMA dest stays linear, rule #21).
//
// Block->XCD map: XCD x (= bx&7, m09) gets bm in {4x..4x+3} x bn 0..7:
// 32 blocks share 4 A-panels (4 MB, L2-resident) + sweep B k-slices in
// cadence (256 KB working set) -> L2-fill collapses vs per-XCD full-A refetch.
// ---------------------------------------------------------------------------
__global__ __launch_bounds__(512, 2) void gemm_epi(
    const unsigned short* __restrict__ A,   // xs  bf16 [BB][FF]
    const unsigned short* __restrict__ Bm,  // means bf16 [CC][FF]
    const float* __restrict__ x2,           // [BB]
    const float* __restrict__ m2,           // [CC]
    float* __restrict__ expo,               // [BB][CC]
    float* __restrict__ cum) {              // [BB][CC]
    __shared__ __align__(16) unsigned short As[4][256 * 32];
    __shared__ __align__(16) unsigned short Bs[4][256 * 32];

    const int t = threadIdx.x;
    const int wave = t >> 6, lane = t & 63;
    const int bx = blockIdx.x;
    const int xcd = bx & 7, q = bx >> 3;                // q = 0..31 within XCD
    const int bm = xcd * 4 + (q >> 3);                  // 0..31
    const int bn = q & 7;                               // 0..7
    const int rowA0 = bm * 256, rowB0 = bn * 256;
    const int wm = wave >> 2, wn = wave & 3;

    // staging: wave writes 16 rows x 64B linear per instruction.
    // lane -> row-in-group lane>>2, slot-in-row lane&3; source 16B-chunk is
    // the inverse swizzle  c = slot ^ ((row>>1)&3)  (16-row groups preserve
    // (row>>1)&3 == (sr>>1)&3 since bases are multiples of 16).
    const int sr = lane >> 2;                           // 0..15
    const int sc = ((lane & 3) ^ ((sr >> 1) & 3)) * 8;  // source col (shorts)
    const unsigned short* gA0 = A  + (size_t)(rowA0 +       wave * 16 + sr) * FF + sc;
    const unsigned short* gA1 = A  + (size_t)(rowA0 + 128 + wave * 16 + sr) * FF + sc;
    const unsigned short* gB0 = Bm + (size_t)(rowB0 +       wave * 16 + sr) * FF + sc;
    const unsigned short* gB1 = Bm + (size_t)(rowB0 + 128 + wave * 16 + sr) * FF + sc;
    const int ldsOff = wave * 16 * 32;                  // shorts

    // fragment reads (mfma 16x16x32: row = lane&15, k-half = lane>>4)
    const int rl = lane & 15, kb = lane >> 4;
    const int pcol = (kb ^ ((rl >> 1) & 3)) * 8;        // phys col (shorts)
    const int arow = (wm * 128 + rl) * 32 + pcol;
    const int brow = (wn * 64  + rl) * 32 + pcol;

    f32x4 acc[8][4] = {};

    auto STAGE = [&](int slot, int kc) {
        const int ko = kc * 32;
        async_copy16(gA0 + ko, &As[slot][ldsOff]);
        async_copy16(gA1 + ko, &As[slot][128 * 32 + ldsOff]);
        async_copy16(gB0 + ko, &Bs[slot][ldsOff]);
        async_copy16(gB1 + ko, &Bs[slot][128 * 32 + ldsOff]);
    };
    auto COMPUTE = [&](int slot) {
        bf16x8 bfr[4], af[8];
#pragma unroll
        for (int j = 0; j < 4; ++j) bfr[j] = *(const bf16x8*)&Bs[slot][brow + j * 16 * 32];
#pragma unroll
        for (int i = 0; i < 8; ++i) af[i] = *(const bf16x8*)&As[slot][arow + i * 16 * 32];
        __builtin_amdgcn_s_setprio(1);
#pragma unroll
        for (int i = 0; i < 8; ++i)
#pragma unroll
            for (int j = 0; j < 4; ++j)
                acc[i][j] = __builtin_amdgcn_mfma_f32_16x16x32_bf16(af[i], bfr[j], acc[i][j], 0, 0, 0);
        __builtin_amdgcn_s_setprio(0);
    };

    // prologue: 3 chunks in flight (12 loads)
    STAGE(0, 0); STAGE(1, 1); STAGE(2, 2);

    // phases 0..59 (stage chunks 3..62): entering phase u, chunks u..u+2 are
    // in flight (12 loads); vmcnt(8) lands chunk u.
#pragma unroll 4
    for (int u = 0; u < 60; ++u) {
        asm volatile("s_waitcnt vmcnt(8)" ::: "memory");
        __builtin_amdgcn_s_barrier();
        __builtin_amdgcn_sched_barrier(0);
        STAGE((u + 3) & 3, u + 3);
        COMPUTE(u & 3);
    }
    // phase 60: stage the last chunk (63)
    asm volatile("s_waitcnt vmcnt(8)" ::: "memory");
    __builtin_amdgcn_s_barrier();
    __builtin_amdgcn_sched_barrier(0);
    STAGE(3, 63);
    COMPUTE(0);
    // phases 61..63: drain 8 -> 4 -> 0
    asm volatile("s_waitcnt vmcnt(8)" ::: "memory");
    __builtin_amdgcn_s_barrier();
    __builtin_amdgcn_sched_barrier(0);
    COMPUTE(1);
    asm volatile("s_waitcnt vmcnt(4)" ::: "memory");
    __builtin_amdgcn_s_barrier();
    __builtin_amdgcn_sched_barrier(0);
    COMPUTE(2);
    asm volatile("s_waitcnt vmcnt(0)" ::: "memory");
    __builtin_amdgcn_s_barrier();
    __builtin_amdgcn_sched_barrier(0);
    COMPUTE(3);

    // epilogue: C/D layout col = lane&15, row = (lane>>4)*4 + reg  [m89/m91]
    const int ln = lane & 15, lq = lane >> 4;
    const int grow0 = rowA0 + wm * 128 + lq * 4;
    const int gcol0 = rowB0 + wn * 64 + ln;
    float m2v[4];
#pragma unroll
    for (int j = 0; j < 4; ++j) m2v[j] = m2[gcol0 + j * 16];

#pragma unroll
    for (int i = 0; i < 8; ++i) {
        float x2r[4];
#pragma unroll
        for (int r = 0; r < 4; ++r) x2r[r] = x2[grow0 + i * 16 + r];
#pragma unroll
        for (int j = 0; j < 4; ++j)
#pragma unroll
            for (int r = 0; r < 4; ++r) {
                const float d2 = x2r[r] + m2v[j] - 2.0f * acc[i][j][r];
                const float d = sqrtf(fmaxf(d2, 0.0f));
                const size_t idx = (size_t)(grow0 + i * 16 + r) * CC + (gcol0 + j * 16);
                __builtin_nontemporal_store(d, &cum[idx]);  // never re-read
                expo[idx] = -d;                              // re-read by softmax
            }
    }
}

// ---------------------------------------------------------------------------
// softmax over each row of exponent -> probs. one block (256 thr) per row.
// No max-subtraction: d = sqrt(x2+m2-2c) <= sqrt(~4500) < 68, so
// exp(-d) >= 3e-30 >> FLT_MIN — unshifted exp is safe and exact enough.
// ---------------------------------------------------------------------------
__global__ void softmax_rows(const float* __restrict__ e, float* __restrict__ p) {
    const int row = blockIdx.x;
    const int t = threadIdx.x;
    const size_t base = (size_t)row * CC + (size_t)t * 8;
    const float4 a = *(const float4*)(e + base);
    const float4 b = *(const float4*)(e + base + 4);
    float ev[8] = {__expf(a.x), __expf(a.y), __expf(a.z), __expf(a.w),
                   __expf(b.x), __expf(b.y), __expf(b.z), __expf(b.w)};
    float s = 0.0f;
#pragma unroll
    for (int i = 0; i < 8; ++i) s += ev[i];
#pragma unroll
    for (int off = 32; off > 0; off >>= 1) s += __shfl_down(s, off);
    __shared__ float reds[4];
    if ((t & 63) == 0) reds[t >> 6] = s;
    __syncthreads();
    s = (reds[0] + reds[1]) + (reds[2] + reds[3]);
    const float inv = 1.0f / s;

    f32x4 o0 = {ev[0] * inv, ev[1] * inv, ev[2] * inv, ev[3] * inv};
    f32x4 o1 = {ev[4] * inv, ev[5] * inv, ev[6] * inv, ev[7] * inv};
    __builtin_nontemporal_store(o0, (f32x4*)(p + base));
    __builtin_nontemporal_store(o1, (f32x4*)(p + base + 4));
}

// ---------------------------------------------------------------------------
extern "C" void kernel_launch(void* const* d_in, const int* in_sizes, int n_in,
                              void* d_out, int out_size, void* d_ws, size_t ws_size,
                              hipStream_t stream) {
    const float* x     = (const float*)d_in[0];   // [BB][FF]
    const float* means = (const float*)d_in[1];   // [CC][FF]
    const float* var   = (const float*)d_in[2];   // [1]
    float* out = (float*)d_out;

    // workspace layout: xb bf16 [BB*FF] | mb bf16 [CC*FF] | x2 f32[BB] | m2 f32[CC]
    unsigned short* xb = (unsigned short*)d_ws;
    unsigned short* mb = xb + (size_t)BB * FF;
    float* x2 = (float*)(mb + (size_t)CC * FF);
    float* m2 = x2 + BB;

    float* probs = out;                          // output 0
    float* expo  = out + (size_t)BB * CC;        // output 1
    float* cum   = expo + (size_t)BB * CC;       // output 2

    prep_rows<<<BB + CC, 256, 0, stream>>>(x, means, xb, mb, x2, m2, var);
    gemm_epi<<<(BB / 256) * (CC / 256), 512, 0, stream>>>(xb, mb, x2, m2, expo, cum);
    softmax_rows<<<BB, 256, 0, stream>>>(expo, probs);
}